// Round 12
// baseline (67.830 us; speedup 1.0000x reference)
//
#include <hip/hip_runtime.h>
#include <math.h>

typedef float f32x16 __attribute__((ext_vector_type(16)));
typedef float f32x4 __attribute__((ext_vector_type(4)));
typedef _Float16 f16x8 __attribute__((ext_vector_type(8)));

#define N_NODES 2048
#define WHT_STRIDE 2208   // f16 elements per padded whT row (4416 B: 64 distinct 256B offsets)

__device__ __forceinline__ float elu1(float v) { return v > 0.f ? v : expm1f(v); }

__device__ __forceinline__ unsigned enc_f(float x) {
    unsigned b = __float_as_uint(x);
    return (b & 0x80000000u) ? ~b : (b | 0x80000000u);
}
__device__ __forceinline__ float dec_f(unsigned u) {
    unsigned b = (u & 0x80000000u) ? (u ^ 0x80000000u) : ~u;
    return __uint_as_float(b);
}

// Stage 1: Wh = X@Ws -> whTp (fp16, d-major, padded rows) + s,t + per-batch max(t).
__global__ __launch_bounds__(256) void gat_stage1(
    const float* __restrict__ X, const float* __restrict__ Ws, const float* __restrict__ av,
    _Float16* __restrict__ whTp, float* __restrict__ sv, float* __restrict__ tvv,
    unsigned* __restrict__ tmaxU) {
    __shared__ float xls[64][66];
    __shared__ float wss[64][64];
    __shared__ float avs[128];
    int tid = threadIdx.x;
    int b = blockIdx.x >> 5;
    int j0 = (blockIdx.x & 31) * 64;
    const float* Xb = X + ((long)(b * N_NODES + j0)) * 64;
#pragma unroll
    for (int k = 0; k < 4; ++k) {
        int i4 = k * 256 + tid;
        float4 v = *reinterpret_cast<const float4*>(Xb + i4 * 4);
        int row = i4 >> 4, c = (i4 & 15) * 4;
        *reinterpret_cast<float2*>(&xls[row][c]) = make_float2(v.x, v.y);
        *reinterpret_cast<float2*>(&xls[row][c + 2]) = make_float2(v.z, v.w);
        *reinterpret_cast<float4*>(&wss[0][0] + i4 * 4) = *reinterpret_cast<const float4*>(Ws + i4 * 4);
    }
    if (tid < 128) avs[tid] = av[tid];
    __syncthreads();
    int row = tid >> 2;
    int dblk = (tid & 3) * 16;
    float acc[16];
#pragma unroll
    for (int k = 0; k < 16; ++k) acc[k] = 0.f;
#pragma unroll 8
    for (int f = 0; f < 64; ++f) {
        float xv = xls[row][f];
        const float4* wr = reinterpret_cast<const float4*>(&wss[f][dblk]);
        float4 w0 = wr[0], w1 = wr[1], w2 = wr[2], w3 = wr[3];
        acc[0]  += xv * w0.x; acc[1]  += xv * w0.y; acc[2]  += xv * w0.z; acc[3]  += xv * w0.w;
        acc[4]  += xv * w1.x; acc[5]  += xv * w1.y; acc[6]  += xv * w1.z; acc[7]  += xv * w1.w;
        acc[8]  += xv * w2.x; acc[9]  += xv * w2.y; acc[10] += xv * w2.z; acc[11] += xv * w2.w;
        acc[12] += xv * w3.x; acc[13] += xv * w3.y; acc[14] += xv * w3.z; acc[15] += xv * w3.w;
    }
    float sp = 0.f, tp = 0.f;
#pragma unroll
    for (int k = 0; k < 16; ++k) {
        int d = dblk + k;
        whTp[(long)(b * 64 + d) * WHT_STRIDE + j0 + row] = (_Float16)acc[k];
        sp += acc[k] * avs[d];
        tp += acc[k] * avs[64 + d];
    }
    sp += __shfl_xor(sp, 1, 64); sp += __shfl_xor(sp, 2, 64);
    tp += __shfl_xor(tp, 1, 64); tp += __shfl_xor(tp, 2, 64);
    if ((tid & 3) == 0) {
        sv[b * N_NODES + j0 + row] = sp;
        tvv[b * N_NODES + j0 + row] = tp;
    }
    float tw = tp;
#pragma unroll
    for (int off = 4; off < 64; off <<= 1) tw = fmaxf(tw, __shfl_xor(tw, off, 64));
    if ((tid & 63) == 0) atomicMax(tmaxU + b, enc_f(tw));
}

// Stage 2: WAVE-LOCAL fused masked-softmax attention. NO barriers, NO main-loop LDS.
// Each wave owns (b, 32-row i-tile, j-slice of N/JS). A-frag built in registers
// (lane: row=lane&31, kgroup=lane>>5); B-frags read direct from padded whT (L2).
// 3-set register rotation, 2-step prefetch lead. acc = 2 x f32x16 (d 0-31 / 32-63).
template<int JS, int LOG2JS, bool DIRECT>
__global__ __launch_bounds__(256, 2) void gat_stage2(
    const float* __restrict__ A, const _Float16* __restrict__ whTp,
    const float* __restrict__ sv, const float* __restrict__ tvv,
    const unsigned* __restrict__ tmaxU,
    float* __restrict__ numw, float* __restrict__ denw, float* __restrict__ H) {
    const int SL = N_NODES / JS;          // j-slice length
    const int NSTEP = SL / 16;            // MFMA k-steps
    int tid = threadIdx.x;
    int wid = tid >> 6, lane = tid & 63;
    int nb = gridDim.x;
    int bid = ((int)blockIdx.x & 7) * (nb >> 3) + ((int)blockIdx.x >> 3);  // XCD chunked
    int gw = bid * 4 + wid;
    int js = gw & (JS - 1);
    int rest = gw >> LOG2JS;
    int it = rest & 63;
    int b = rest >> 6;
    int i0 = it * 32;
    int rowA = lane & 31, kg = lane >> 5;

    float s_reg = sv[b * N_NODES + i0 + rowA];
    float Tb = dec_f(tmaxU[b]);
    float m0 = s_reg + Tb;
    float Ci = fmaxf(m0, 0.2f * m0) - 5.0f;   // exponents <= 5 -> fp16-safe
    float den = 0.f;

    const float* pA = A + ((long)(b * N_NODES + i0 + rowA)) * N_NODES + js * SL + kg * 8;
    const float* pT = tvv + b * N_NODES + js * SL + kg * 8;
    const _Float16* pB0 = whTp + (long)(b * 64 + rowA) * WHT_STRIDE + js * SL + kg * 8;
    const _Float16* pB1 = pB0 + 32 * WHT_STRIDE;

    f32x16 acc0, acc1;
#pragma unroll
    for (int r = 0; r < 16; ++r) { acc0[r] = 0.f; acc1[r] = 0.f; }

    // 3 register sets (A8 + T8 + 2xB f16x8 each)
    f32x4 aA0, aA1, tA0, tA1, aB0, aB1, tB0, tB1, aC0, aC1, tC0, tC1;
    f16x8 bA0, bA1, bB0, bB1, bC0, bC1;

    // prologue: sets A,B <- steps 0,1
    aA0 = *reinterpret_cast<const f32x4*>(pA);
    aA1 = *reinterpret_cast<const f32x4*>(pA + 4);
    tA0 = *reinterpret_cast<const f32x4*>(pT);
    tA1 = *reinterpret_cast<const f32x4*>(pT + 4);
    bA0 = *reinterpret_cast<const f16x8*>(pB0);
    bA1 = *reinterpret_cast<const f16x8*>(pB1);
    aB0 = *reinterpret_cast<const f32x4*>(pA + 16);
    aB1 = *reinterpret_cast<const f32x4*>(pA + 20);
    tB0 = *reinterpret_cast<const f32x4*>(pT + 16);
    tB1 = *reinterpret_cast<const f32x4*>(pT + 20);
    bB0 = *reinterpret_cast<const f16x8*>(pB0 + 16);
    bB1 = *reinterpret_cast<const f16x8*>(pB1 + 16);

#define EXP1(AV, TV, QD)                                                   \
    { float e_ = s_reg + (TV); e_ = fmaxf(e_, 0.2f * e_);                  \
      float p_ = (AV) * __expf(e_ - Ci);                                   \
      QD = (_Float16)p_; den += (float)QD; }

#define STEP(c, CA0, CA1, CT0, CT1, CB0, CB1, NA0, NA1, NT0, NT1, NB0, NB1) \
    {                                                                       \
        int cn = (c) + 2 < NSTEP ? (c) + 2 : NSTEP - 1;                     \
        NA0 = *reinterpret_cast<const f32x4*>(pA + cn * 16);                \
        NA1 = *reinterpret_cast<const f32x4*>(pA + cn * 16 + 4);            \
        NT0 = *reinterpret_cast<const f32x4*>(pT + cn * 16);                \
        NT1 = *reinterpret_cast<const f32x4*>(pT + cn * 16 + 4);            \
        NB0 = *reinterpret_cast<const f16x8*>(pB0 + cn * 16);               \
        NB1 = *reinterpret_cast<const f16x8*>(pB1 + cn * 16);               \
        _Float16 q0, q1, q2, q3, q4, q5, q6, q7;                            \
        EXP1(CA0.x, CT0.x, q0) EXP1(CA0.y, CT0.y, q1)                       \
        EXP1(CA0.z, CT0.z, q2) EXP1(CA0.w, CT0.w, q3)                       \
        EXP1(CA1.x, CT1.x, q4) EXP1(CA1.y, CT1.y, q5)                       \
        EXP1(CA1.z, CT1.z, q6) EXP1(CA1.w, CT1.w, q7)                       \
        f16x8 af = {q0, q1, q2, q3, q4, q5, q6, q7};                        \
        acc0 = __builtin_amdgcn_mfma_f32_32x32x16_f16(af, CB0, acc0, 0, 0, 0); \
        acc1 = __builtin_amdgcn_mfma_f32_32x32x16_f16(af, CB1, acc1, 0, 0, 0); \
    }

#pragma unroll 1
    for (int c = 0; c + 3 <= NSTEP; c += 3) {
        STEP(c,     aA0, aA1, tA0, tA1, bA0, bA1, aC0, aC1, tC0, tC1, bC0, bC1)
        STEP(c + 1, aB0, aB1, tB0, tB1, bB0, bB1, aA0, aA1, tA0, tA1, bA0, bA1)
        STEP(c + 2, aC0, aC1, tC0, tC1, bC0, bC1, aB0, aB1, tB0, tB1, bB0, bB1)
    }
    if (NSTEP % 3 == 2) {
        STEP(NSTEP - 2, aA0, aA1, tA0, tA1, bA0, bA1, aC0, aC1, tC0, tC1, bC0, bC1)
        STEP(NSTEP - 1, aB0, aB1, tB0, tB1, bB0, bB1, aA0, aA1, tA0, tA1, bA0, bA1)
    } else if (NSTEP % 3 == 1) {
        STEP(NSTEP - 1, aA0, aA1, tA0, tA1, bA0, bA1, aC0, aC1, tC0, tC1, bC0, bC1)
    }
#undef STEP
#undef EXP1

    // row denominator: lanes l and l+32 hold the two k-group partials of row l&31
    den += __shfl_xor(den, 32, 64);
    int col = lane & 31;

    if (DIRECT) {
        float dinv = 1.f / den;
#pragma unroll
        for (int r = 0; r < 16; ++r) {
            int row = (r & 3) + 8 * (r >> 2) + 4 * kg;
            float* Hrow = H + ((long)(b * N_NODES + i0 + row)) * 64 + col;
            Hrow[0]  = elu1(acc0[r] * dinv);
            Hrow[32] = elu1(acc1[r] * dinv);
        }
    } else {
#pragma unroll
        for (int r = 0; r < 16; ++r) {
            int row = (r & 3) + 8 * (r >> 2) + 4 * kg;
            long base = ((long)((js * 8 + b) * N_NODES + i0 + row)) * 64 + col;
            numw[base]      = acc0[r];
            numw[base + 32] = acc1[r];
        }
        if (lane < 32) denw[(js * 8 + b) * N_NODES + i0 + lane] = den;
    }
}

// Combine JS j-split partials: H = elu(sum(num)/sum(den))
template<int JS>
__global__ __launch_bounds__(256) void gat_combine(
    const float* __restrict__ numw, const float* __restrict__ denw, float* __restrict__ H) {
    int f4 = blockIdx.x * 256 + threadIdx.x;    // 262144 float4s
    long e0 = (long)f4 * 4;
    int row = f4 >> 4;
    float nx = 0.f, ny = 0.f, nz = 0.f, nw = 0.f, d = 0.f;
#pragma unroll
    for (int s = 0; s < JS; ++s) {
        float4 v = *reinterpret_cast<const float4*>(numw + (long)s * (8L * N_NODES * 64) + e0);
        nx += v.x; ny += v.y; nz += v.z; nw += v.w;
        d += denw[s * 8 * N_NODES + row];
    }
    float dinv = 1.f / d;
    f32x4 o;
    o.x = elu1(nx * dinv); o.y = elu1(ny * dinv);
    o.z = elu1(nz * dinv); o.w = elu1(nw * dinv);
    __builtin_nontemporal_store(o, reinterpret_cast<f32x4*>(H + e0));
}

extern "C" void kernel_launch(void* const* d_in, const int* in_sizes, int n_in,
                              void* d_out, int out_size, void* d_ws, size_t ws_size,
                              hipStream_t stream) {
    const float* A  = (const float*)d_in[0];   // [8,2048,2048]
    const float* X  = (const float*)d_in[1];   // [8,2048,64]
    const float* Ws = (const float*)d_in[2];   // [64,64]
    const float* av = (const float*)d_in[3];   // [128,1]
    float* H = (float*)d_out;                  // [8,2048,64]

    char* ws = (char*)d_ws;
    _Float16* whTp = (_Float16*)ws;                      // 8*64*2208*2 = 2,260,992 B
    float* sv = (float*)(ws + 0x240000);                 // 64 KiB
    float* tv = (float*)(ws + 0x250000);                 // 64 KiB
    unsigned* tmaxU = (unsigned*)(ws + 0x260000);        // 4 KiB
    float* denw = (float*)(ws + 0x261000);               // up to 4*64 KiB
    float* numw = (float*)(ws + 0x2B0000);               // JS * 4 MiB
    const size_t need4 = 0x2B0000 + 4L * 8 * N_NODES * 64 * 4;   // ~19.6 MB
    const size_t need2 = 0x2B0000 + 2L * 8 * N_NODES * 64 * 4;   // ~11.2 MB

    hipMemsetAsync(tmaxU, 0, 8 * sizeof(unsigned), stream);
    gat_stage1<<<256, 256, 0, stream>>>(X, Ws, av, whTp, sv, tv, tmaxU);
    if (ws_size >= need4) {
        gat_stage2<4, 2, false><<<512, 256, 0, stream>>>(A, whTp, sv, tv, tmaxU, numw, denw, H);
        gat_combine<4><<<1024, 256, 0, stream>>>(numw, denw, H);
    } else if (ws_size >= need2) {
        gat_stage2<2, 1, false><<<256, 256, 0, stream>>>(A, whTp, sv, tv, tmaxU, numw, denw, H);
        gat_combine<2><<<1024, 256, 0, stream>>>(numw, denw, H);
    } else {
        gat_stage2<1, 0, true><<<128, 256, 0, stream>>>(A, whTp, sv, tv, tmaxU, nullptr, nullptr, H);
    }
}

// Round 13
// 53.185 us; speedup vs baseline: 1.2754x; 1.2754x over previous
//
#include <hip/hip_runtime.h>
#include <math.h>

typedef float f32x16 __attribute__((ext_vector_type(16)));
typedef float f32x4 __attribute__((ext_vector_type(4)));
typedef _Float16 f16x8 __attribute__((ext_vector_type(8)));
typedef _Float16 f16x4 __attribute__((ext_vector_type(4)));

#define N_NODES 2048
#define SCHED_FENCE() __builtin_amdgcn_sched_barrier(0)

__device__ __forceinline__ void gload16(const void* g, void* l) {
    __builtin_amdgcn_global_load_lds(
        (__attribute__((address_space(1))) void*)(uintptr_t)g,
        (__attribute__((address_space(3))) void*)l, 16, 0, 0);
}

__device__ __forceinline__ float elu1(float v) { return v > 0.f ? v : expm1f(v); }

__device__ __forceinline__ unsigned enc_f(float x) {
    unsigned b = __float_as_uint(x);
    return (b & 0x80000000u) ? ~b : (b | 0x80000000u);
}
__device__ __forceinline__ float dec_f(unsigned u) {
    unsigned b = (u & 0x80000000u) ? (u ^ 0x80000000u) : ~u;
    return __uint_as_float(b);
}

// Stage 1: Wh = X@Ws -> whT (fp16, d-major, XOR-swizzled rows) + s,t + per-batch max(t).
__global__ __launch_bounds__(256) void gat_stage1(
    const float* __restrict__ X, const float* __restrict__ Ws, const float* __restrict__ av,
    _Float16* __restrict__ whT, float* __restrict__ sv, float* __restrict__ tvv,
    unsigned* __restrict__ tmaxU) {
    __shared__ float xls[64][66];
    __shared__ float wss[64][64];
    __shared__ float avs[128];
    int tid = threadIdx.x;
    int b = blockIdx.x >> 5;
    int j0 = (blockIdx.x & 31) * 64;
    const float* Xb = X + ((long)(b * N_NODES + j0)) * 64;
#pragma unroll
    for (int k = 0; k < 4; ++k) {
        int i4 = k * 256 + tid;
        float4 v = *reinterpret_cast<const float4*>(Xb + i4 * 4);
        int row = i4 >> 4, c = (i4 & 15) * 4;
        *reinterpret_cast<float2*>(&xls[row][c]) = make_float2(v.x, v.y);
        *reinterpret_cast<float2*>(&xls[row][c + 2]) = make_float2(v.z, v.w);
        *reinterpret_cast<float4*>(&wss[0][0] + i4 * 4) = *reinterpret_cast<const float4*>(Ws + i4 * 4);
    }
    if (tid < 128) avs[tid] = av[tid];
    __syncthreads();
    int row = tid >> 2;
    int dblk = (tid & 3) * 16;
    float acc[16];
#pragma unroll
    for (int k = 0; k < 16; ++k) acc[k] = 0.f;
#pragma unroll 8
    for (int f = 0; f < 64; ++f) {
        float xv = xls[row][f];
        const float4* wr = reinterpret_cast<const float4*>(&wss[f][dblk]);
        float4 w0 = wr[0], w1 = wr[1], w2 = wr[2], w3 = wr[3];
        acc[0]  += xv * w0.x; acc[1]  += xv * w0.y; acc[2]  += xv * w0.z; acc[3]  += xv * w0.w;
        acc[4]  += xv * w1.x; acc[5]  += xv * w1.y; acc[6]  += xv * w1.z; acc[7]  += xv * w1.w;
        acc[8]  += xv * w2.x; acc[9]  += xv * w2.y; acc[10] += xv * w2.z; acc[11] += xv * w2.w;
        acc[12] += xv * w3.x; acc[13] += xv * w3.y; acc[14] += xv * w3.z; acc[15] += xv * w3.w;
    }
    float sp = 0.f, tp = 0.f;
#pragma unroll
    for (int k = 0; k < 16; ++k) {
        int d = dblk + k;
        long gidx = ((long)(b * 64 + d) << 11) + j0 + (row ^ ((d & 7) << 3));  // swizzled
        whT[gidx] = (_Float16)acc[k];
        sp += acc[k] * avs[d];
        tp += acc[k] * avs[64 + d];
    }
    sp += __shfl_xor(sp, 1, 64); sp += __shfl_xor(sp, 2, 64);
    tp += __shfl_xor(tp, 1, 64); tp += __shfl_xor(tp, 2, 64);
    if ((tid & 3) == 0) {
        sv[b * N_NODES + j0 + row] = sp;
        tvv[b * N_NODES + j0 + row] = tp;
    }
    float tw = tp;
#pragma unroll
    for (int off = 4; off < 64; off <<= 1) tw = fmaxf(tw, __shfl_xor(tw, off, 64));
    if ((tid & 63) == 0) atomicMax(tmaxU + b, enc_f(tw));
}

// Stage 2: r6-EXACT schedule, fp16 single-plane payload.
// 512 threads (8 waves), TI=32 rows, JT=64 chunks, NC=32.
// whT x4 x8KB LDS bufs (DMA lead 2, G issued FIRST each body); A/t 4-slot 2-chunk-lead
// rotation; wt x2 x4KB; ONE barrier + ONE MFMA per chunk. LDS = 40KB.
__global__ __launch_bounds__(512, 4) void gat_stage2(
    const float* __restrict__ A, const _Float16* __restrict__ whT,
    const float* __restrict__ sv, const float* __restrict__ tvv,
    const unsigned* __restrict__ tmaxU, float* __restrict__ H) {
    __shared__ __align__(16) char lds[40960];
    // whT bufs [4] x 8KB at 0..32768; wt [2] x 4KB at 32768/36864.
    // epilogue: numl 4x8KB at 0..32768; den at 32768 (wt buf0; last MFMA uses buf1).
    const int NC = 32;
    int tid = threadIdx.x;
    int nb = gridDim.x;  // 512
    int bid = ((int)blockIdx.x & 7) * (nb >> 3) + ((int)blockIdx.x >> 3);  // XCD x <-> batch b=x
    int b = bid >> 6;
    int it = bid & 63;
    int i0 = it * 32;
    int wid = tid >> 6, lane = tid & 63;

    int jq = tid & 15;             // j-quad
    int irow = tid >> 4;           // 0..31
    int sd = tid >> 3, sseg = tid & 7;
    const _Float16* src = whT + (((long)(b * 64 + sd)) << 11) + sseg * 8;
    int waveOff = wid * 1024;

    float s_reg = sv[b * N_NODES + i0 + irow];
    float Tb = dec_f(tmaxU[b]);
    float m0 = s_reg + Tb;
    float Ci = fmaxf(m0, 0.2f * m0) - 5.0f;   // exponents <= 5 -> fp16-safe
    float den = 0.f;
    const float* Abase = A + ((long)(b * N_NODES + i0 + irow)) * N_NODES + jq * 4;
    const float* tb = tvv + b * N_NODES + jq * 4;

    f32x16 acc;
#pragma unroll
    for (int r = 0; r < 16; ++r) acc[r] = 0.f;

    int iAm = lane & 31;
    int dB = (wid & 1) * 32 + (lane & 31);
    int jby = (wid >> 1) * 32 + (lane >> 5) * 16;
    int offA = iAm * 128 + (jby ^ ((iAm & 7) << 4));
    int offB = dB * 128 + (jby ^ ((dB & 7) << 4));
    int wtOff = irow * 128 + ((jq * 8) ^ ((irow & 7) << 4));

    f32x4 a0, a1, a2, a3, t0, t1, t2, t3;
    // prologue: G(0),G(1) FIRST, then A/t chunks 0,1 (r6 order)
    gload16(src, lds + waveOff);
    gload16(src + 64, lds + 8192 + waveOff);
    SCHED_FENCE();
    a0 = *reinterpret_cast<const f32x4*>(Abase);
    t0 = *reinterpret_cast<const f32x4*>(tb);
    a1 = *reinterpret_cast<const f32x4*>(Abase + 64);
    t1 = *reinterpret_cast<const f32x4*>(tb + 64);
    SCHED_FENCE();

#define CHUNK_BODY(c, A_IN, T_IN, A_OUT, T_OUT)                                          \
    {                                                                                     \
        int cn = (c) + 2 < NC ? (c) + 2 : NC - 1;                                         \
        gload16(src + cn * 64, lds + (cn & 3) * 8192 + waveOff);  /* G first */           \
        SCHED_FENCE();                                                                    \
        A_OUT = *reinterpret_cast<const f32x4*>(Abase + cn * 64);                         \
        T_OUT = *reinterpret_cast<const f32x4*>(tb + cn * 64);                            \
        SCHED_FENCE();                                                                    \
        { char* wt = lds + 32768 + ((c) & 1) * 4096;                                      \
          float e0 = s_reg + T_IN.x, e1 = s_reg + T_IN.y;                                 \
          float e2 = s_reg + T_IN.z, e3 = s_reg + T_IN.w;                                 \
          e0 = fmaxf(e0, 0.2f * e0); e1 = fmaxf(e1, 0.2f * e1);                           \
          e2 = fmaxf(e2, 0.2f * e2); e3 = fmaxf(e3, 0.2f * e3);                           \
          float w0 = A_IN.x * __expf(e0 - Ci), w1 = A_IN.y * __expf(e1 - Ci);             \
          float w2 = A_IN.z * __expf(e2 - Ci), w3 = A_IN.w * __expf(e3 - Ci);             \
          _Float16 q0 = (_Float16)w0, q1 = (_Float16)w1;                                  \
          _Float16 q2 = (_Float16)w2, q3 = (_Float16)w3;                                  \
          den += (float)q0 + (float)q1 + (float)q2 + (float)q3;                           \
          f16x4 wv = {q0, q1, q2, q3};                                                    \
          *reinterpret_cast<f16x4*>(wt + wtOff) = wv; }                                   \
        asm volatile("s_waitcnt lgkmcnt(0)" ::: "memory");                                \
        __builtin_amdgcn_s_barrier();                                                     \
        SCHED_FENCE();                                                                    \
        { char* whb = lds + ((c) & 3) * 8192;                                             \
          char* wtb = lds + 32768 + ((c) & 1) * 4096;                                     \
          f16x8 af = *reinterpret_cast<const f16x8*>(wtb + offA);                         \
          f16x8 bh = *reinterpret_cast<const f16x8*>(whb + offB);                         \
          __builtin_amdgcn_s_setprio(1);                                                  \
          acc = __builtin_amdgcn_mfma_f32_32x32x16_f16(af, bh, acc, 0, 0, 0);             \
          __builtin_amdgcn_s_setprio(0); }                                                \
        SCHED_FENCE();                                                                    \
    }

#pragma unroll 1
    for (int c4 = 0; c4 < NC; c4 += 4) {
        CHUNK_BODY(c4 + 0, a0, t0, a2, t2)
        CHUNK_BODY(c4 + 1, a1, t1, a3, t3)
        CHUNK_BODY(c4 + 2, a2, t2, a0, t0)
        CHUNK_BODY(c4 + 3, a3, t3, a1, t1)
    }
#undef CHUNK_BODY

    // drain clamp-replicated tail DMAs before reusing staging LDS
    asm volatile("s_waitcnt vmcnt(0)" ::: "memory");
    __syncthreads();
    // scatter acc into per-k-slice regions numl[js][32][64] at js*8192
    {
        float* numl = (float*)(lds + (wid >> 1) * 8192);
        int colD = (wid & 1) * 32 + (lane & 31);
        int rb = 4 * (lane >> 5);
#pragma unroll
        for (int r = 0; r < 16; ++r)
            numl[((r & 3) + 8 * (r >> 2) + rb) * 64 + colD] = acc[r];
    }
    // denominator: reduce over the 16 jq lanes of each i-row
#pragma unroll
    for (int off = 1; off < 16; off <<= 1) den += __shfl_xor(den, off, 64);
    float* den_lds = (float*)(lds + 32768);
    if ((tid & 15) == 0) den_lds[irow] = den;
    __syncthreads();
    // output: thread = (row, 4 cols); sum 4 k-slice partials, divide, elu
    {
        int row = tid >> 4, col4 = (tid & 15) * 4;
        float4 n0 = *reinterpret_cast<float4*>(lds + 0 * 8192 + row * 256 + col4 * 4);
        float4 n1 = *reinterpret_cast<float4*>(lds + 1 * 8192 + row * 256 + col4 * 4);
        float4 n2 = *reinterpret_cast<float4*>(lds + 2 * 8192 + row * 256 + col4 * 4);
        float4 n3 = *reinterpret_cast<float4*>(lds + 3 * 8192 + row * 256 + col4 * 4);
        float dinv = 1.f / den_lds[row];
        f32x4 o;
        o.x = elu1((n0.x + n1.x + n2.x + n3.x) * dinv);
        o.y = elu1((n0.y + n1.y + n2.y + n3.y) * dinv);
        o.z = elu1((n0.z + n1.z + n2.z + n3.z) * dinv);
        o.w = elu1((n0.w + n1.w + n2.w + n3.w) * dinv);
        float* Hrow = H + ((long)(b * N_NODES + i0 + row)) * 64 + col4;
        __builtin_nontemporal_store(o, reinterpret_cast<f32x4*>(Hrow));
    }
}

extern "C" void kernel_launch(void* const* d_in, const int* in_sizes, int n_in,
                              void* d_out, int out_size, void* d_ws, size_t ws_size,
                              hipStream_t stream) {
    const float* A  = (const float*)d_in[0];   // [8,2048,2048]
    const float* X  = (const float*)d_in[1];   // [8,2048,64]
    const float* Ws = (const float*)d_in[2];   // [64,64]
    const float* av = (const float*)d_in[3];   // [128,1]
    float* H = (float*)d_out;                  // [8,2048,64]

    char* ws = (char*)d_ws;
    _Float16* whT = (_Float16*)ws;                           // 2 MiB
    float* sv = (float*)(ws + (1L << 21));                   // 64 KiB
    float* tv = (float*)(ws + (1L << 21) + 65536);           // 64 KiB
    unsigned* tmaxU = (unsigned*)(ws + (1L << 21) + 131072); // 32 B

    hipMemsetAsync(tmaxU, 0, 8 * sizeof(unsigned), stream);
    gat_stage1<<<256, 256, 0, stream>>>(X, Ws, av, whT, sv, tv, tmaxU);
    gat_stage2<<<512, 512, 0, stream>>>(A, whT, sv, tv, tmaxU, H);
}

// Round 14
// 52.263 us; speedup vs baseline: 1.2979x; 1.0176x over previous
//
#include <hip/hip_runtime.h>
#include <math.h>

typedef float f32x16 __attribute__((ext_vector_type(16)));
typedef float f32x4 __attribute__((ext_vector_type(4)));
typedef _Float16 f16x8 __attribute__((ext_vector_type(8)));
typedef _Float16 f16x4 __attribute__((ext_vector_type(4)));

#define N_NODES 2048
#define SCHED_FENCE() __builtin_amdgcn_sched_barrier(0)

__device__ __forceinline__ void gload16(const void* g, void* l) {
    __builtin_amdgcn_global_load_lds(
        (__attribute__((address_space(1))) void*)(uintptr_t)g,
        (__attribute__((address_space(3))) void*)l, 16, 0, 0);
}

__device__ __forceinline__ float elu1(float v) { return v > 0.f ? v : expm1f(v); }

__device__ __forceinline__ unsigned enc_f(float x) {
    unsigned b = __float_as_uint(x);
    return (b & 0x80000000u) ? ~b : (b | 0x80000000u);
}
__device__ __forceinline__ float dec_f(unsigned u) {
    unsigned b = (u & 0x80000000u) ? (u ^ 0x80000000u) : ~u;
    return __uint_as_float(b);
}

// Stage 1: Wh = X@Ws -> whT (fp16, d-major, XOR-swizzled rows) + s,t + per-batch max(t).
__global__ __launch_bounds__(256) void gat_stage1(
    const float* __restrict__ X, const float* __restrict__ Ws, const float* __restrict__ av,
    _Float16* __restrict__ whT, float* __restrict__ sv, float* __restrict__ tvv,
    unsigned* __restrict__ tmaxU) {
    __shared__ float xls[64][66];
    __shared__ float wss[64][64];
    __shared__ float avs[128];
    int tid = threadIdx.x;
    int b = blockIdx.x >> 5;
    int j0 = (blockIdx.x & 31) * 64;
    const float* Xb = X + ((long)(b * N_NODES + j0)) * 64;
#pragma unroll
    for (int k = 0; k < 4; ++k) {
        int i4 = k * 256 + tid;
        float4 v = *reinterpret_cast<const float4*>(Xb + i4 * 4);
        int row = i4 >> 4, c = (i4 & 15) * 4;
        *reinterpret_cast<float2*>(&xls[row][c]) = make_float2(v.x, v.y);
        *reinterpret_cast<float2*>(&xls[row][c + 2]) = make_float2(v.z, v.w);
        *reinterpret_cast<float4*>(&wss[0][0] + i4 * 4) = *reinterpret_cast<const float4*>(Ws + i4 * 4);
    }
    if (tid < 128) avs[tid] = av[tid];
    __syncthreads();
    int row = tid >> 2;
    int dblk = (tid & 3) * 16;
    float acc[16];
#pragma unroll
    for (int k = 0; k < 16; ++k) acc[k] = 0.f;
#pragma unroll 8
    for (int f = 0; f < 64; ++f) {
        float xv = xls[row][f];
        const float4* wr = reinterpret_cast<const float4*>(&wss[f][dblk]);
        float4 w0 = wr[0], w1 = wr[1], w2 = wr[2], w3 = wr[3];
        acc[0]  += xv * w0.x; acc[1]  += xv * w0.y; acc[2]  += xv * w0.z; acc[3]  += xv * w0.w;
        acc[4]  += xv * w1.x; acc[5]  += xv * w1.y; acc[6]  += xv * w1.z; acc[7]  += xv * w1.w;
        acc[8]  += xv * w2.x; acc[9]  += xv * w2.y; acc[10] += xv * w2.z; acc[11] += xv * w2.w;
        acc[12] += xv * w3.x; acc[13] += xv * w3.y; acc[14] += xv * w3.z; acc[15] += xv * w3.w;
    }
    float sp = 0.f, tp = 0.f;
#pragma unroll
    for (int k = 0; k < 16; ++k) {
        int d = dblk + k;
        long gidx = ((long)(b * 64 + d) << 11) + j0 + (row ^ ((d & 7) << 3));  // swizzled
        whT[gidx] = (_Float16)acc[k];
        sp += acc[k] * avs[d];
        tp += acc[k] * avs[64 + d];
    }
    sp += __shfl_xor(sp, 1, 64); sp += __shfl_xor(sp, 2, 64);
    tp += __shfl_xor(tp, 1, 64); tp += __shfl_xor(tp, 2, 64);
    if ((tid & 3) == 0) {
        sv[b * N_NODES + j0 + row] = sp;
        tvv[b * N_NODES + j0 + row] = tp;
    }
    float tw = tp;
#pragma unroll
    for (int off = 4; off < 64; off <<= 1) tw = fmaxf(tw, __shfl_xor(tw, off, 64));
    if ((tid & 63) == 0) atomicMax(tmaxU + b, enc_f(tw));
}

// Stage 2: fp16 payload, DEPTH-4 pipeline.
// 512 threads (8 waves), TI=32 rows, JT=64, NC=32.
// whT x8 x8KB LDS bufs (DMA lead 4, G issued FIRST); A/t two 4-slot banks (lead 4);
// wt x2 x4KB; ONE barrier + ONE MFMA per chunk. LDS = 72KB -> 2 blocks/CU.
__global__ __launch_bounds__(512, 4) void gat_stage2(
    const float* __restrict__ A, const _Float16* __restrict__ whT,
    const float* __restrict__ sv, const float* __restrict__ tvv,
    const unsigned* __restrict__ tmaxU, float* __restrict__ H) {
    __shared__ __align__(16) char lds[73728];
    // whT bufs [8] x 8KB at 0..65536; wt [2] x 4KB at 65536/69632.
    // epilogue: numl 4x8KB at 0..32768; den at 65536 (wt buf0; last chunk uses buf1).
    const int NC = 32;
    int tid = threadIdx.x;
    int nb = gridDim.x;  // 512
    int bid = ((int)blockIdx.x & 7) * (nb >> 3) + ((int)blockIdx.x >> 3);  // XCD x <-> batch b=x
    int b = bid >> 6;
    int it = bid & 63;
    int i0 = it * 32;
    int wid = tid >> 6, lane = tid & 63;

    int jq = tid & 15;             // j-quad
    int irow = tid >> 4;           // 0..31
    int sd = tid >> 3, sseg = tid & 7;
    const _Float16* src = whT + (((long)(b * 64 + sd)) << 11) + sseg * 8;
    int waveOff = wid * 1024;

    float s_reg = sv[b * N_NODES + i0 + irow];
    float Tb = dec_f(tmaxU[b]);
    float m0 = s_reg + Tb;
    float Ci = fmaxf(m0, 0.2f * m0) - 5.0f;   // exponents <= 5 -> fp16-safe
    float den = 0.f;
    const float* Abase = A + ((long)(b * N_NODES + i0 + irow)) * N_NODES + jq * 4;
    const float* tb = tvv + b * N_NODES + jq * 4;

    f32x16 acc;
#pragma unroll
    for (int r = 0; r < 16; ++r) acc[r] = 0.f;

    int iAm = lane & 31;
    int dB = (wid & 1) * 32 + (lane & 31);
    int jby = (wid >> 1) * 32 + (lane >> 5) * 16;
    int offA = iAm * 128 + (jby ^ ((iAm & 7) << 4));
    int offB = dB * 128 + (jby ^ ((dB & 7) << 4));
    int wtOff = irow * 128 + ((jq * 8) ^ ((irow & 7) << 4));

    // two 4-slot banks for A and t (lead 4)
    f32x4 aP0, aP1, aP2, aP3, aQ0, aQ1, aQ2, aQ3;
    f32x4 tP0, tP1, tP2, tP3, tQ0, tQ1, tQ2, tQ3;

    // prologue: G(0..3) FIRST, then A/t(0..3) into bank P
    gload16(src,       lds + 0 * 8192 + waveOff);
    gload16(src + 64,  lds + 1 * 8192 + waveOff);
    gload16(src + 128, lds + 2 * 8192 + waveOff);
    gload16(src + 192, lds + 3 * 8192 + waveOff);
    SCHED_FENCE();
    aP0 = *reinterpret_cast<const f32x4*>(Abase);
    tP0 = *reinterpret_cast<const f32x4*>(tb);
    aP1 = *reinterpret_cast<const f32x4*>(Abase + 64);
    tP1 = *reinterpret_cast<const f32x4*>(tb + 64);
    aP2 = *reinterpret_cast<const f32x4*>(Abase + 128);
    tP2 = *reinterpret_cast<const f32x4*>(tb + 128);
    aP3 = *reinterpret_cast<const f32x4*>(Abase + 192);
    tP3 = *reinterpret_cast<const f32x4*>(tb + 192);
    SCHED_FENCE();

#define CHUNK_BODY(c, BUFW, A_IN, T_IN, A_OUT, T_OUT)                                    \
    {                                                                                     \
        int cn = (c) + 4 < NC ? (c) + 4 : NC - 1;                                         \
        gload16(src + cn * 64, lds + (BUFW) * 8192 + waveOff);   /* G first */            \
        SCHED_FENCE();                                                                    \
        A_OUT = *reinterpret_cast<const f32x4*>(Abase + cn * 64);                         \
        T_OUT = *reinterpret_cast<const f32x4*>(tb + cn * 64);                            \
        SCHED_FENCE();                                                                    \
        { char* wt = lds + 65536 + ((c) & 1) * 4096;                                      \
          float e0 = s_reg + T_IN.x, e1 = s_reg + T_IN.y;                                 \
          float e2 = s_reg + T_IN.z, e3 = s_reg + T_IN.w;                                 \
          e0 = fmaxf(e0, 0.2f * e0); e1 = fmaxf(e1, 0.2f * e1);                           \
          e2 = fmaxf(e2, 0.2f * e2); e3 = fmaxf(e3, 0.2f * e3);                           \
          float w0 = A_IN.x * __expf(e0 - Ci), w1 = A_IN.y * __expf(e1 - Ci);             \
          float w2 = A_IN.z * __expf(e2 - Ci), w3 = A_IN.w * __expf(e3 - Ci);             \
          _Float16 q0 = (_Float16)w0, q1 = (_Float16)w1;                                  \
          _Float16 q2 = (_Float16)w2, q3 = (_Float16)w3;                                  \
          den += (float)q0 + (float)q1 + (float)q2 + (float)q3;                           \
          f16x4 wv = {q0, q1, q2, q3};                                                    \
          *reinterpret_cast<f16x4*>(wt + wtOff) = wv; }                                   \
        asm volatile("s_waitcnt lgkmcnt(0)" ::: "memory");                                \
        __builtin_amdgcn_s_barrier();                                                     \
        SCHED_FENCE();                                                                    \
        { char* whb = lds + ((c) & 7) * 8192;                                             \
          char* wtb = lds + 65536 + ((c) & 1) * 4096;                                     \
          f16x8 af = *reinterpret_cast<const f16x8*>(wtb + offA);                         \
          f16x8 bh = *reinterpret_cast<const f16x8*>(whb + offB);                         \
          __builtin_amdgcn_s_setprio(1);                                                  \
          acc = __builtin_amdgcn_mfma_f32_32x32x16_f16(af, bh, acc, 0, 0, 0);             \
          __builtin_amdgcn_s_setprio(0); }                                                \
        SCHED_FENCE();                                                                    \
    }

#pragma unroll 1
    for (int c8 = 0; c8 < NC; c8 += 8) {
        CHUNK_BODY(c8 + 0, 4, aP0, tP0, aQ0, tQ0)
        CHUNK_BODY(c8 + 1, 5, aP1, tP1, aQ1, tQ1)
        CHUNK_BODY(c8 + 2, 6, aP2, tP2, aQ2, tQ2)
        CHUNK_BODY(c8 + 3, 7, aP3, tP3, aQ3, tQ3)
        CHUNK_BODY(c8 + 4, 0, aQ0, tQ0, aP0, tP0)
        CHUNK_BODY(c8 + 5, 1, aQ1, tQ1, aP1, tP1)
        CHUNK_BODY(c8 + 6, 2, aQ2, tQ2, aP2, tP2)
        CHUNK_BODY(c8 + 7, 3, aQ3, tQ3, aP3, tP3)
    }
#undef CHUNK_BODY

    // drain clamp-replicated tail DMAs before reusing staging LDS
    asm volatile("s_waitcnt vmcnt(0)" ::: "memory");
    __syncthreads();
    // scatter acc into per-k-slice regions numl[js][32][64] at js*8192
    {
        float* numl = (float*)(lds + (wid >> 1) * 8192);
        int colD = (wid & 1) * 32 + (lane & 31);
        int rb = 4 * (lane >> 5);
#pragma unroll
        for (int r = 0; r < 16; ++r)
            numl[((r & 3) + 8 * (r >> 2) + rb) * 64 + colD] = acc[r];
    }
    // denominator: reduce over the 16 jq lanes of each i-row
#pragma unroll
    for (int off = 1; off < 16; off <<= 1) den += __shfl_xor(den, off, 64);
    float* den_lds = (float*)(lds + 65536);
    if ((tid & 15) == 0) den_lds[irow] = den;
    __syncthreads();
    // output: thread = (row, 4 cols); sum 4 k-slice partials, divide, elu
    {
        int row = tid >> 4, col4 = (tid & 15) * 4;
        float4 n0 = *reinterpret_cast<float4*>(lds + 0 * 8192 + row * 256 + col4 * 4);
        float4 n1 = *reinterpret_cast<float4*>(lds + 1 * 8192 + row * 256 + col4 * 4);
        float4 n2 = *reinterpret_cast<float4*>(lds + 2 * 8192 + row * 256 + col4 * 4);
        float4 n3 = *reinterpret_cast<float4*>(lds + 3 * 8192 + row * 256 + col4 * 4);
        float dinv = 1.f / den_lds[row];
        f32x4 o;
        o.x = elu1((n0.x + n1.x + n2.x + n3.x) * dinv);
        o.y = elu1((n0.y + n1.y + n2.y + n3.y) * dinv);
        o.z = elu1((n0.z + n1.z + n2.z + n3.z) * dinv);
        o.w = elu1((n0.w + n1.w + n2.w + n3.w) * dinv);
        float* Hrow = H + ((long)(b * N_NODES + i0 + row)) * 64 + col4;
        __builtin_nontemporal_store(o, reinterpret_cast<f32x4*>(Hrow));
    }
}

extern "C" void kernel_launch(void* const* d_in, const int* in_sizes, int n_in,
                              void* d_out, int out_size, void* d_ws, size_t ws_size,
                              hipStream_t stream) {
    const float* A  = (const float*)d_in[0];   // [8,2048,2048]
    const float* X  = (const float*)d_in[1];   // [8,2048,64]
    const float* Ws = (const float*)d_in[2];   // [64,64]
    const float* av = (const float*)d_in[3];   // [128,1]
    float* H = (float*)d_out;                  // [8,2048,64]

    char* ws = (char*)d_ws;
    _Float16* whT = (_Float16*)ws;                           // 2 MiB
    float* sv = (float*)(ws + (1L << 21));                   // 64 KiB
    float* tv = (float*)(ws + (1L << 21) + 65536);           // 64 KiB
    unsigned* tmaxU = (unsigned*)(ws + (1L << 21) + 131072); // 32 B

    hipMemsetAsync(tmaxU, 0, 8 * sizeof(unsigned), stream);
    gat_stage1<<<256, 256, 0, stream>>>(X, Ws, av, whT, sv, tv, tmaxU);
    gat_stage2<<<512, 512, 0, stream>>>(A, whT, sv, tv, tmaxU, H);
}